// Round 15
// baseline (219.481 us; speedup 1.0000x reference)
//
#include <hip/hip_runtime.h>

#define NPOS 1600
#define DIMC 128
#define NHEADS 8
#define CHD 16

// ---------------- workspace layout (floats) ----------------
// 0        xrt     204800   (x + LN(pe(x)), position-major [1600][128])
// 204800   qraw    204800   (channel-major, pre-norm q)
// 409600   kv1t    409600   (1600 x 256, position-major)
// 819200   kinv    128      (per-head per-channel 1/||k||)
// 1024000  vt      204800   (position-major [h][m][16])
// 1228800  pewt    16384    \
// 1245184  kvt     32768     } transient (qt region)
// 1277952  projt   32768    /
// 1228800  qt      204800
// 1433600  kt      204800   (raw k, position-major [h][m][16])
// 1638400  xt/outA 204800
// 1843200  w1t     147456
// 1990656  w2t     147456
// 2138112  outwt   16384

__device__ __forceinline__ float wsum(float v) {
#pragma unroll
  for (int off = 1; off < 64; off <<= 1) v += __shfl_xor(v, off);
  return v;
}
// packed fp32 (2x rate)
__device__ __forceinline__ void pk_fma(float2& d, float2 a, float2 b) {
  asm("v_pk_fma_f32 %0, %1, %2, %0" : "+v"(d) : "v"(a), "v"(b));
}
__device__ __forceinline__ float2 pk_mul(float2 a, float2 b) {
  float2 d;
  asm("v_pk_mul_f32 %0, %1, %2" : "=v"(d) : "v"(a), "v"(b));
  return d;
}

// -------- one-time weight transposes + x transpose --------
__global__ __launch_bounds__(256) void k_prep(
    const float* __restrict__ w1, const float* __restrict__ w2,
    const float* __restrict__ proj, const float* __restrict__ kvw,
    const float* __restrict__ outw, const float* __restrict__ pew,
    const float* __restrict__ x,
    float* __restrict__ w1t, float* __restrict__ w2t,
    float* __restrict__ projt, float* __restrict__ kvt,
    float* __restrict__ outwt, float* __restrict__ pewt,
    float* __restrict__ xt) {
  int bid = blockIdx.x;
  int t = threadIdx.x;
  __shared__ float tile[DIMC][17];
  if (bid < 576) {
    int idx = bid * 256 + t;
    if (idx < 9 * DIMC * DIMC) {
      int k = idx / (DIMC * DIMC);
      int rem = idx % (DIMC * DIMC);
      int i = rem >> 7, o = rem & 127;
      w1t[idx] = w1[(o * DIMC + i) * 9 + k];
      w2t[idx] = w2[(o * DIMC + i) * 9 + k];
    }
    if (idx < 256 * DIMC) {
      int ic = idx >> 7, o = idx & 127;
      projt[idx] = proj[o * 256 + ic];
    }
    if (idx < DIMC * 256) {
      int i = idx >> 8, oc = idx & 255;
      kvt[idx] = kvw[oc * DIMC + i];
    }
    if (idx < DIMC * DIMC) {
      int i = idx >> 7, o = idx & 127;
      outwt[idx] = outw[o * DIMC + i];
      pewt[idx] = pew[o * DIMC + i];
    }
  } else {
    int n0 = (bid - 576) * 16;
#pragma unroll
    for (int pass = 0; pass < 2; pass++) {
      int ch = (t >> 2) + pass * 64, q = t & 3;
      float4 v = *(const float4*)(x + (size_t)ch * NPOS + n0 + q * 4);
      tile[ch][q * 4 + 0] = v.x; tile[ch][q * 4 + 1] = v.y;
      tile[ch][q * 4 + 2] = v.z; tile[ch][q * 4 + 3] = v.w;
    }
    __syncthreads();
    int pos = t >> 4, c8 = (t & 15) * 8;
#pragma unroll
    for (int k = 0; k < 8; k++)
      xt[(size_t)(n0 + pos) * DIMC + c8 + k] = tile[c8 + k][pos];
  }
}

// -------- pe (1x1 conv) + LayerNorm(ch) + residual; 256 threads, split-K --------
__global__ __launch_bounds__(256) void k_pe_ln(
    const float* __restrict__ xt, const float* __restrict__ pewt,
    const float* __restrict__ pb, const float* __restrict__ lg,
    const float* __restrict__ lb, float* __restrict__ xrt) {
  int n0 = blockIdx.x * 4;
  int t = threadIdx.x;
  int ch = t & 127, half = t >> 7;
  __shared__ __align__(16) float xc[4][DIMC];
  __shared__ float pacc[2][4][DIMC];
  __shared__ float red[2][2][4];
  if (t < 128) {
    int pos = t >> 5, c4 = t & 31;
    *(float4*)&xc[pos][c4 * 4] =
        *(const float4*)(xt + (size_t)(n0 + pos) * DIMC + c4 * 4);
  }
  __syncthreads();
  {
    float a[4] = {0.f, 0.f, 0.f, 0.f};
    int i0 = half * 64;
    for (int i = i0; i < i0 + 64; i++) {
      float wv = pewt[i * DIMC + ch];
#pragma unroll
      for (int p = 0; p < 4; p++) a[p] += wv * xc[p][i];
    }
#pragma unroll
    for (int p = 0; p < 4; p++) pacc[half][p][ch] = a[p];
  }
  __syncthreads();
  if (t < 128) {
    float pbv = pb[t];
    float acc[4];
#pragma unroll
    for (int p = 0; p < 4; p++) acc[p] = pacc[0][p][t] + pacc[1][p][t] + pbv;
    int w = t >> 6, lane = t & 63;
    {
      float s0 = wsum(acc[0]), s1 = wsum(acc[1]), s2 = wsum(acc[2]), s3 = wsum(acc[3]);
      if (lane == 0) { red[0][w][0] = s0; red[0][w][1] = s1; red[0][w][2] = s2; red[0][w][3] = s3; }
    }
    __builtin_amdgcn_wave_barrier();
    asm volatile("s_waitcnt lgkmcnt(0)" ::: "memory");
    __builtin_amdgcn_s_barrier();
    float mu[4];
#pragma unroll
    for (int p = 0; p < 4; p++) mu[p] = (red[0][0][p] + red[0][1][p]) * (1.f / 128.f);
    {
      float d0 = acc[0] - mu[0], d1 = acc[1] - mu[1], d2 = acc[2] - mu[2], d3 = acc[3] - mu[3];
      float q0 = wsum(d0 * d0), q1 = wsum(d1 * d1), q2 = wsum(d2 * d2), q3 = wsum(d3 * d3);
      if (lane == 0) { red[1][w][0] = q0; red[1][w][1] = q1; red[1][w][2] = q2; red[1][w][3] = q3; }
    }
    __builtin_amdgcn_wave_barrier();
    asm volatile("s_waitcnt lgkmcnt(0)" ::: "memory");
    __builtin_amdgcn_s_barrier();
    float lgv = lg[t], lbv = lb[t];
#pragma unroll
    for (int p = 0; p < 4; p++) {
      float var = (red[1][0][p] + red[1][1][p]) * (1.f / 128.f);
      float tv = (acc[p] - mu[p]) * rsqrtf(var + 1e-5f) * lgv + lbv;
      xrt[(size_t)(n0 + p) * DIMC + t] = xc[p][t] + tv;
    }
  } else {
    __builtin_amdgcn_s_barrier();
    __builtin_amdgcn_s_barrier();
  }
}

// -------- merged: ASPP+proj (0..799, 2-col strips) | kv 1x1 (800..1199) --------
__global__ __launch_bounds__(256) void k_aspp_kv1(
    const float* __restrict__ xrt, const float* __restrict__ w1t,
    const float* __restrict__ w2t, const float* __restrict__ bg1,
    const float* __restrict__ bb1, const float* __restrict__ bm1,
    const float* __restrict__ bv1, const float* __restrict__ bg2,
    const float* __restrict__ bb2, const float* __restrict__ bm2,
    const float* __restrict__ bv2, const float* __restrict__ projt,
    const float* __restrict__ bgp, const float* __restrict__ bbp,
    const float* __restrict__ bmp, const float* __restrict__ bvp,
    float* __restrict__ q,
    const float* __restrict__ kvt, float* __restrict__ kv1t) {
  int t = threadIdx.x;
  if (blockIdx.x < 800) {
    int strip = blockIdx.x;
    int r = strip / 20, c0 = (strip % 20) * 2;
    int ch = t & 127, br = t >> 7;
    __shared__ __align__(16) float xs[2][DIMC][2];
    __shared__ __align__(16) float cat[2 * DIMC][2];
    float aa[2] = {0.f, 0.f};
    int dil = br ? 5 : 3;
    const float* wt = br ? w2t : w1t;
    for (int k = 0; k < 9; k++) {
      int dr = k / 3 - 1, dc = k % 3 - 1;
      int rr = r + dil * dr;
#pragma unroll
      for (int p = 0; p < 2; p++) {
        int cc = c0 + p + dil * dc;
        xs[br][ch][p] = (rr >= 0 && rr < 40 && cc >= 0 && cc < 40)
                            ? xrt[(size_t)(rr * 40 + cc) * DIMC + ch] : 0.f;
      }
      __syncthreads();
      const float* wrow = wt + (size_t)k * DIMC * DIMC + ch;
      for (int i = 0; i < DIMC; i++) {
        float wv = wrow[i * DIMC];
        aa[0] += wv * xs[br][i][0];
        aa[1] += wv * xs[br][i][1];
      }
      __syncthreads();
    }
    float sc = br ? bg2[ch] * rsqrtf(bv2[ch] + 1e-5f) : bg1[ch] * rsqrtf(bv1[ch] + 1e-5f);
    float bm = br ? bm2[ch] : bm1[ch];
    float bb = br ? bb2[ch] : bb1[ch];
#pragma unroll
    for (int p = 0; p < 2; p++) cat[br * DIMC + ch][p] = fmaxf((aa[p] - bm) * sc + bb, 0.f);
    __syncthreads();
    float qa = 0.f;
    for (int j = 0; j < 256; j++) {
      float wv = projt[j * DIMC + ch];
      qa += wv * cat[j][br];
    }
    float scp = bgp[ch] * rsqrtf(bvp[ch] + 1e-5f);
    q[ch * NPOS + r * 40 + c0 + br] = fmaxf((qa - bmp[ch]) * scp + bbp[ch], 0.f);
  } else {
    int n0 = (blockIdx.x - 800) * 4;
    __shared__ __align__(16) float xc[4][DIMC];
    if (t < 128) {
      int pos = t >> 5, c4 = t & 31;
      *(float4*)&xc[pos][c4 * 4] =
          *(const float4*)(xrt + (size_t)(n0 + pos) * DIMC + c4 * 4);
    }
    __syncthreads();
    float acc[4] = {0.f, 0.f, 0.f, 0.f};
    for (int i = 0; i < DIMC; i++) {
      float w = kvt[i * 256 + t];
#pragma unroll
      for (int p = 0; p < 4; p++) acc[p] += w * xc[p][i];
    }
#pragma unroll
    for (int p = 0; p < 4; p++) kv1t[(n0 + p) * 256 + t] = acc[p];
  }
}

// -------- depthwise 3x3 (0..799): k raw -> position-major kt, v -> vt
//          | q L2-norm (800..927) --------
__global__ __launch_bounds__(256) void k_dw(const float* __restrict__ kv1t,
                                            const float* __restrict__ dww,
                                            float* __restrict__ kt,
                                            float* __restrict__ vt,
                                            const float* __restrict__ qraw,
                                            float* __restrict__ qt) {
  int t = threadIdx.x;
  if (blockIdx.x < 800) {
    int strip = blockIdx.x;
    int r = strip / 20, c0 = (strip % 20) * 2;
    float wl[9];
#pragma unroll
    for (int k = 0; k < 9; k++) wl[k] = dww[t * 9 + k];
    __builtin_amdgcn_s_setprio(1);
    for (int p = 0; p < 2; p++) {
      int c = c0 + p;
      float acc = 0.f;
#pragma unroll
      for (int kh = 0; kh < 3; kh++) {
        int rr = r + kh - 1;
        if (rr < 0 || rr >= 40) continue;
#pragma unroll
        for (int kw_ = 0; kw_ < 3; kw_++) {
          int cc = c + kw_ - 1;
          if (cc < 0 || cc >= 40) continue;
          acc += wl[kh * 3 + kw_] * kv1t[(rr * 40 + cc) * 256 + t];
        }
      }
      int pos = r * 40 + c;
      if (t < DIMC) {
        kt[((size_t)(t >> 4) * NPOS + pos) * CHD + (t & 15)] = acc;  // raw k, pos-major
      } else {
        int cv = t - DIMC;
        vt[((size_t)(cv >> 4) * NPOS + pos) * CHD + (cv & 15)] = acc;
      }
    }
    __builtin_amdgcn_s_setprio(0);
  } else {
    // q-channel L2 norm (depends only on qraw, concurrent with dw work)
    int ch = blockIdx.x - 800;
    __shared__ float wred[4];
    float ss = 0.f;
    for (int m = t; m < NPOS; m += 256) {
      float v = qraw[ch * NPOS + m];
      ss += v * v;
    }
    ss = wsum(ss);
    if ((t & 63) == 0) wred[t >> 6] = ss;
    __syncthreads();
    float tot = wred[0] + wred[1] + wred[2] + wred[3];
    float inv = 1.0f / fmaxf(sqrtf(tot), 1e-12f);
    int h = ch >> 4, c = ch & 15;
    for (int m = t; m < NPOS; m += 256)
      qt[((size_t)(h * NPOS) + m) * CHD + c] = qraw[ch * NPOS + m] * inv;
  }
}

// -------- per-head per-channel 1/||k|| (8 blocks, coalesced reads) --------
__global__ __launch_bounds__(256) void k_kinv(const float* __restrict__ kt,
                                              float* __restrict__ kinv) {
  int h = blockIdx.x, t = threadIdx.x;
  int c = t & 15, sub = t >> 4;  // lane = (sub&3)*16 + c
  __shared__ float red[4][16];
  const float* base = kt + (size_t)h * NPOS * CHD;
  float ss = 0.f;
  for (int m = sub; m < NPOS; m += 16) {
    float v = base[(size_t)m * CHD + c];
    ss += v * v;
  }
  // reduce over sub&3 (lane bits 4,5)
  ss += __shfl_xor(ss, 16);
  ss += __shfl_xor(ss, 32);
  int w = t >> 6, lane = t & 63;
  if (lane < 16) red[w][lane] = ss;
  __syncthreads();
  if (t < 16) {
    float tot = red[0][t] + red[1][t] + red[2][t] + red[3][t];
    kinv[h * CHD + t] = 1.0f / fmaxf(sqrtf(tot), 1e-12f);
  }
}

// -------- fused attention: 4 rows/block, wave-per-row select; kinv folded into Q --------
#define RANK_STEP(INCL, S0, S1, S2, S3, REM, TT)                         \
  {                                                                      \
    int abv = (INCL) - (S0);                                             \
    int ge1 = abv + (S1), ge2 = abv + (S2), ge3 = abv + (S3);            \
    bool hit = ((INCL) >= (REM)) && (abv < (REM));                       \
    bool c0_ = hit && (ge1 < (REM));                                     \
    bool c1_ = hit && (ge1 >= (REM)) && (ge2 < (REM));                   \
    bool c2_ = hit && (ge2 >= (REM)) && (ge3 < (REM));                   \
    int bl = c0_ ? 4 * lane : c1_ ? 4 * lane + 1                         \
           : c2_ ? 4 * lane + 2 : 4 * lane + 3;                          \
    int gl = c0_ ? ge1 : c1_ ? ge2 : c2_ ? ge3 : abv;                    \
    unsigned long long bal = __ballot(hit);                              \
    int wl = (int)__ffsll(bal) - 1;                                      \
    TT |= ((unsigned)__shfl(bl, wl)) << ls;                              \
    REM -= __shfl(gl, wl);                                               \
  }

__device__ __forceinline__ float dec_u(unsigned uu) {
  int bits = (uu & 0x80000000u) ? (int)(uu ^ 0x80000000u) : (int)(~uu);
  return __int_as_float(bits);
}

__global__ __launch_bounds__(256) void k_attn(
    const float* __restrict__ qt, const float* __restrict__ kt,
    const float* __restrict__ vt, const float* __restrict__ kinv,
    const float* __restrict__ temp,
    const float* __restrict__ a1p, const float* __restrict__ a2p,
    const float* __restrict__ a3p, const float* __restrict__ a4p,
    float* __restrict__ outA) {
  __shared__ unsigned hist[2][4][4][256];  // [buf][row][group|copy][bin], 32 KB
  __shared__ unsigned s_thr[4][4];
  __shared__ float s_z[4][16];
  __shared__ float s_wr[4][64];

  int tid = threadIdx.x;
  int lane = tid & 63, w = tid >> 6;
  int n0 = blockIdx.x * 4;
  int h = blockIdx.y;

  float tmpr = temp[h];
  const float* kbase = kt + (size_t)h * NPOS * CHD;
  const float* vbase = vt + (size_t)h * NPOS * CHD;

  float2 qreg[4][8];
  {
    const float4* q4 = (const float4*)(qt + ((size_t)h * NPOS + n0) * CHD);
    const float* kh = kinv + h * CHD;
    float2 kin[8];
#pragma unroll
    for (int j = 0; j < 8; j++) kin[j] = make_float2(kh[2 * j], kh[2 * j + 1]);
#pragma unroll
    for (int r = 0; r < 4; r++)
#pragma unroll
      for (int j = 0; j < 4; j++) {
        float4 a = q4[r * 4 + j];
        qreg[r][2 * j] = pk_mul(make_float2(a.x, a.y), kin[2 * j]);
        qreg[r][2 * j + 1] = pk_mul(make_float2(a.z, a.w), kin[2 * j + 1]);
      }
  }

#pragma unroll
  for (int k = 0; k < 4; k++) ((uint4*)hist)[tid + k * 256] = make_uint4(0u, 0u, 0u, 0u);

  unsigned u[4][7];
  __builtin_amdgcn_s_setprio(1);
#pragma unroll
  for (int i = 0; i < 7; i++) {
    int m = tid + (i << 8);
    const float4* k4 = (const float4*)(kbase + (size_t)m * CHD);
    float4 ka = k4[0], kb = k4[1], kc = k4[2], kd = k4[3];
    bool valid = (m < NPOS);
#pragma unroll
    for (int r = 0; r < 4; r++) {
      float2 e = pk_mul(make_float2(ka.x, ka.y), qreg[r][0]);
      pk_fma(e, make_float2(ka.z, ka.w), qreg[r][1]);
      pk_fma(e, make_float2(kb.x, kb.y), qreg[r][2]);
      pk_fma(e, make_float2(kb.z, kb.w), qreg[r][3]);
      pk_fma(e, make_float2(kc.x, kc.y), qreg[r][4]);
      pk_fma(e, make_float2(kc.z, kc.w), qreg[r][5]);
      pk_fma(e, make_float2(kd.x, kd.y), qreg[r][6]);
      pk_fma(e, make_float2(kd.z, kd.w), qreg[r][7]);
      float s = (e.x + e.y) * tmpr;
      int bi = __float_as_int(s);
      unsigned uu = ((unsigned)bi) ^ ((bi < 0) ? 0xFFFFFFFFu : 0x80000000u);
      u[r][i] = valid ? uu : 0x00800000u;
    }
  }
  __builtin_amdgcn_s_setprio(0);
  __syncthreads();

  unsigned tw0 = 0, tw1 = 0, tw2 = 0, tw3 = 0;
  int rw0 = 800, rw1 = 1066, rw2 = 1200, rw3 = 1280;

#pragma unroll
  for (int level = 3; level >= 1; level--) {
    const int ls = level * 8;
    const unsigned pm = (level == 3) ? 0u : (0xFFFFFFFFu << (ls + 8));
    const int p = (3 - level) & 1;

    if (level == 3) {
      int cpy = ((w & 1) << 1) | (lane & 1);
#pragma unroll
      for (int i = 0; i < 7; i++)
#pragma unroll
        for (int r = 0; r < 4; r++)
          atomicAdd(&hist[p][r][cpy][u[r][i] >> 24], 1u);
    } else {
      unsigned P[4][4];
#pragma unroll
      for (int r = 0; r < 4; r++)
#pragma unroll
        for (int g = 0; g < 4; g++) P[r][g] = s_thr[r][g] & pm;
#pragma unroll
      for (int i = 0; i < 7; i++)
#pragma unroll
        for (int r = 0; r < 4; r++) {
          unsigned uu = u[r][i], pf = uu & pm;
          int g = (pf == P[r][0]) ? 0 : (pf == P[r][1]) ? 1 : (pf == P[r][2]) ? 2
                : (pf == P[r][3]) ? 3 : -1;
          if (g >= 0) atomicAdd(&hist[p][r][g][(uu >> ls) & 255], 1u);
        }
    }
    __syncthreads();

    if (level != 1) {
#pragma unroll
      for (int k = 0; k < 4; k++)
        ((uint4*)(&hist[p ^ 1][0][0][0]))[tid + k * 256] = make_uint4(0u, 0u, 0u, 0u);
    }

    uint4 c0 = *(const uint4*)&hist[p][w][0][lane * 4];
    uint4 c1 = *(const uint4*)&hist[p][w][1][lane * 4];
    uint4 c2 = *(const uint4*)&hist[p][w][2][lane * 4];
    uint4 c3 = *(const uint4*)&hist[p][w][3][lane * 4];
    bool L1, L2, L3;
    if (level == 3) {
      c0.x += c1.x + c2.x + c3.x;
      c0.y += c1.y + c2.y + c3.y;
      c0.z += c1.z + c2.z + c3.z;
      c0.w += c1.w + c2.w + c3.w;
      c1 = make_uint4(0u, 0u, 0u, 0u); c2 = c1; c3 = c1;
      L1 = false; L2 = false; L3 = false;
    } else {
      L1 = ((tw1 & pm) != (tw0 & pm));
      L2 = ((tw2 & pm) != (tw1 & pm));
      L3 = ((tw3 & pm) != (tw2 & pm));
    }

    int s3_0 = c0.w, s2_0 = s3_0 + c0.z, s1_0 = s2_0 + c0.y, s0_0 = s1_0 + c0.x;
    int s3_1 = c1.w, s2_1 = s3_1 + c1.z, s1_1 = s2_1 + c1.y, s0_1 = s1_1 + c1.x;
    int s3_2 = c2.w, s2_2 = s3_2 + c2.z, s1_2 = s2_2 + c2.y, s0_2 = s1_2 + c2.x;
    int s3_3 = c3.w, s2_3 = s3_3 + c3.z, s1_3 = s2_3 + c3.y, s0_3 = s1_3 + c3.x;

    unsigned vA = (unsigned)s0_0 | ((unsigned)s0_1 << 16);
    unsigned vB = (unsigned)s0_2 | ((unsigned)s0_3 << 16);
#pragma unroll
    for (int off = 1; off < 64; off <<= 1) {
      unsigned xA = __shfl_down(vA, off), xB = __shfl_down(vB, off);
      if (lane + off < 64) { vA += xA; vB += xB; }
    }
    int i0 = (int)(vA & 0xFFFFu), i1 = (int)(vA >> 16);
    int i2 = (int)(vB & 0xFFFFu), i3 = (int)(vB >> 16);

    RANK_STEP(i0, s0_0, s1_0, s2_0, s3_0, rw0, tw0);
    int I1 = L1 ? i1 : i0;
    int S0a = L1 ? s0_1 : s0_0, S1a = L1 ? s1_1 : s1_0;
    int S2a = L1 ? s2_1 : s2_0, S3a = L1 ? s3_1 : s3_0;
    RANK_STEP(I1, S0a, S1a, S2a, S3a, rw1, tw1);
    int I2 = L2 ? i2 : I1;
    int S0b = L2 ? s0_2 : S0a, S1b = L2 ? s1_2 : S1a;
    int S2b = L2 ? s2_2 : S2a, S3b = L2 ? s3_2 : S3a;
    RANK_STEP(I2, S0b, S1b, S2b, S3b, rw2, tw2);
    int I3 = L3 ? i3 : I2;
    int S0c = L3 ? s0_3 : S0b, S1c = L3 ? s1_3 : S1b;
    int S2c = L3 ? s2_3 : S2b, S3c = L3 ? s3_3 : S3b;
    RANK_STEP(I3, S0c, S1c, S2c, S3c, rw3, tw3);

    if (lane == 0) {
      s_thr[w][0] = tw0; s_thr[w][1] = tw1;
      s_thr[w][2] = tw2; s_thr[w][3] = tw3;
    }
    __syncthreads();
  }

  unsigned tr[4][4];
#pragma unroll
  for (int r = 0; r < 4; r++)
#pragma unroll
    for (int j = 0; j < 4; j++) tr[r][j] = s_thr[r][j];
  float C[4];
#pragma unroll
  for (int r = 0; r < 4; r++) C[r] = dec_u(tr[r][0]);

  float zacc[4][4];
#pragma unroll
  for (int r = 0; r < 4; r++)
#pragma unroll
    for (int j = 0; j < 4; j++) zacc[r][j] = 0.f;
#pragma unroll
  for (int i = 0; i < 7; i++) {
#pragma unroll
    for (int r = 0; r < 4; r++) {
      unsigned uu = u[r][i];
      float e = __expf(dec_u(uu) - C[r]);
      int b; float ee;
      if (uu >= tr[r][1]) { b = (uu >= tr[r][0]) ? 0 : 1; ee = e; }
      else if (uu >= tr[r][3]) { b = (uu >= tr[r][2]) ? 2 : 3; ee = e; }
      else { b = 3; ee = 0.f; }
      zacc[r][0] += (b == 0) ? ee : 0.f;
      zacc[r][1] += (b <= 1) ? ee : 0.f;
      zacc[r][2] += (b <= 2) ? ee : 0.f;
      zacc[r][3] += ee;
      u[r][i] = (__float_as_uint(ee) & ~3u) | (unsigned)b;
    }
  }
  {
    float zv[16];
#pragma unroll
    for (int r = 0; r < 4; r++)
#pragma unroll
      for (int j = 0; j < 4; j++) zv[r * 4 + j] = zacc[r][j];
#pragma unroll
    for (int k = 0; k < 8; k++) {
      float s = (lane & 1) ? zv[k] : zv[k + 8];
      float x = __shfl_xor(s, 1);
      zv[k] = ((lane & 1) ? zv[k + 8] : zv[k]) + x;
    }
#pragma unroll
    for (int k = 0; k < 4; k++) {
      float s = (lane & 2) ? zv[k] : zv[k + 4];
      float x = __shfl_xor(s, 2);
      zv[k] = ((lane & 2) ? zv[k + 4] : zv[k]) + x;
    }
#pragma unroll
    for (int k = 0; k < 2; k++) {
      float s = (lane & 4) ? zv[k] : zv[k + 2];
      float x = __shfl_xor(s, 4);
      zv[k] = ((lane & 4) ? zv[k + 2] : zv[k]) + x;
    }
    {
      float s = (lane & 8) ? zv[0] : zv[1];
      float x = __shfl_xor(s, 8);
      zv[0] = ((lane & 8) ? zv[1] : zv[0]) + x;
    }
    zv[0] += __shfl_xor(zv[0], 16);
    zv[0] += __shfl_xor(zv[0], 32);
    int zidx = ((lane & 1) << 3) | ((lane & 2) << 1) | ((lane & 4) >> 1) | ((lane & 8) >> 3);
    if (lane < 16) s_z[w][zidx] = zv[0];
  }
  __syncthreads();
  float coef[4][4];
  {
    float A1 = a1p[0], A2 = a2p[0], A3 = a3p[0], A4 = a4p[0];
#pragma unroll
    for (int r = 0; r < 4; r++) {
      float Z0 = s_z[0][r * 4 + 0] + s_z[1][r * 4 + 0] + s_z[2][r * 4 + 0] + s_z[3][r * 4 + 0];
      float Z1 = s_z[0][r * 4 + 1] + s_z[1][r * 4 + 1] + s_z[2][r * 4 + 1] + s_z[3][r * 4 + 1];
      float Z2 = s_z[0][r * 4 + 2] + s_z[1][r * 4 + 2] + s_z[2][r * 4 + 2] + s_z[3][r * 4 + 2];
      float Z3 = s_z[0][r * 4 + 3] + s_z[1][r * 4 + 3] + s_z[2][r * 4 + 3] + s_z[3][r * 4 + 3];
      float c3 = A4 / Z3;
      float c2 = c3 + A3 / Z2;
      float c1 = c2 + A2 / Z1;
      float c0 = c1 + A1 / Z0;
      coef[r][0] = c0; coef[r][1] = c1; coef[r][2] = c2; coef[r][3] = c3;
    }
  }

  float2 o[4][8];
#pragma unroll
  for (int r = 0; r < 4; r++)
#pragma unroll
    for (int j = 0; j < 8; j++) o[r][j] = make_float2(0.f, 0.f);
  __builtin_amdgcn_s_setprio(1);
#pragma unroll
  for (int i = 0; i < 7; i++) {
    int m = tid + (i << 8);
    const float4* v4 = (const float4*)(vbase + (size_t)m * CHD);
    float4 va = v4[0], vb = v4[1], vc = v4[2], vd = v4[3];
#pragma unroll
    for (int r = 0; r < 4; r++) {
      unsigned pe = u[r][i];
      int b = pe & 3;
      float wg = __uint_as_float(pe & ~3u)
               * ((b == 0) ? coef[r][0] : (b == 1) ? coef[r][1] : (b == 2) ? coef[r][2] : coef[r][3]);
      float2 w2 = make_float2(wg, wg);
      pk_fma(o[r][0], make_float2(va.x, va.y), w2);
      pk_fma(o[r][1], make_float2(va.z, va.w), w2);
      pk_fma(o[r][2], make_float2(vb.x, vb.y), w2);
      pk_fma(o[r][3], make_float2(vb.z, vb.w), w2);
      pk_fma(o[r][4], make_float2(vc.x, vc.y), w2);
      pk_fma(o[r][5], make_float2(vc.z, vc.w), w2);
      pk_fma(o[r][6], make_float2(vd.x, vd.y), w2);
      pk_fma(o[r][7], make_float2(vd.z, vd.w), w2);
    }
  }
  __builtin_amdgcn_s_setprio(0);
  {
    float rr[64];
#pragma unroll
    for (int r = 0; r < 4; r++)
#pragma unroll
      for (int j = 0; j < 8; j++) {
        rr[r * 16 + 2 * j] = o[r][j].x;
        rr[r * 16 + 2 * j + 1] = o[r][j].y;
      }
#pragma unroll
    for (int k = 0; k < 32; k++) {
      float s = (lane & 1) ? rr[k] : rr[k + 32];
      float x = __shfl_xor(s, 1);
      rr[k] = ((lane & 1) ? rr[k + 32] : rr[k]) + x;
    }
#pragma unroll
    for (int k = 0; k < 16; k++) {
      float s = (lane & 2) ? rr[k] : rr[k + 16];
      float x = __shfl_xor(s, 2);
      rr[k] = ((lane & 2) ? rr[k + 16] : rr[k]) + x;
    }
#pragma unroll
    for (int k = 0; k < 8; k++) {
      float s = (lane & 4) ? rr[k] : rr[k + 8];
      float x = __shfl_xor(s, 4);
      rr[k] = ((lane & 4) ? rr[k + 8] : rr[k]) + x;
    }
#pragma unroll
    for (int k = 0; k < 4; k++) {
      float s = (lane & 8) ? rr[k] : rr[k + 4];
      float x = __shfl_xor(s, 8);
      rr[k] = ((lane & 8) ? rr[k + 4] : rr[k]) + x;
    }
#pragma unroll
    for (int k = 0; k < 2; k++) {
      float s = (lane & 16) ? rr[k] : rr[k + 2];
      float x = __shfl_xor(s, 16);
      rr[k] = ((lane & 16) ? rr[k + 2] : rr[k]) + x;
    }
    {
      float s = (lane & 32) ? rr[0] : rr[1];
      float x = __shfl_xor(s, 32);
      rr[0] = ((lane & 32) ? rr[1] : rr[0]) + x;
    }
    int idx = ((lane & 1) << 5) | ((lane & 2) << 3) | ((lane & 4) << 1)
            | ((lane & 8) >> 1) | ((lane & 16) >> 3) | ((lane & 32) >> 5);
    s_wr[w][idx] = rr[0];
  }
  __syncthreads();
  if (tid < 64) {
    float v = s_wr[0][tid] + s_wr[1][tid] + s_wr[2][tid] + s_wr[3][tid];
    outA[((size_t)h * NPOS + n0) * CHD + tid] = v;
  }
}

// -------- final 1x1 conv; 256 threads, split-K --------
__global__ __launch_bounds__(256) void k_fconv(const float* __restrict__ outA,
                                               const float* __restrict__ outwt,
                                               float* __restrict__ y) {
  int n0 = blockIdx.x * 4;
  int t = threadIdx.x;
  int ch = t & 127, half = t >> 7;
  __shared__ __align__(16) float oc[4][DIMC];
  __shared__ float pacc[2][4][DIMC];
  if (t < 128) {
    int pos = t >> 5, ch4 = t & 31;
    int head = ch4 >> 2, qq = ch4 & 3;
    float4 v = *(const float4*)(outA + ((size_t)(head * NPOS) + n0 + pos) * CHD + qq * 4);
    *(float4*)&oc[pos][ch4 * 4] = v;
  }
  __syncthreads();
  {
    float a[4] = {0.f, 0.f, 0.f, 0.f};
    int i0 = half * 64;
    for (int i = i0; i < i0 + 64; i++) {
      float wv = outwt[i * DIMC + ch];
#pragma unroll
      for (int p = 0; p < 4; p++) a[p] += wv * oc[p][i];
    }
#pragma unroll
    for (int p = 0; p < 4; p++) pacc[half][p][ch] = a[p];
  }
  __syncthreads();
  if (t < 128) {
#pragma unroll
    for (int p = 0; p < 4; p++)
      y[t * NPOS + n0 + p] = pacc[0][p][t] + pacc[1][p][t];
  }
}

extern "C" void kernel_launch(void* const* d_in, const int* in_sizes, int n_in,
                              void* d_out, int out_size, void* d_ws, size_t ws_size,
                              hipStream_t stream) {
  const float* x = (const float*)d_in[0];
  const float* pe_w = (const float*)d_in[1];
  const float* pe_b = (const float*)d_in[2];
  const float* ln_g = (const float*)d_in[3];
  const float* ln_b = (const float*)d_in[4];
  const float* aspp_w1 = (const float*)d_in[5];
  const float* bn1_g = (const float*)d_in[6];
  const float* bn1_b = (const float*)d_in[7];
  const float* bn1_m = (const float*)d_in[8];
  const float* bn1_v = (const float*)d_in[9];
  const float* aspp_w2 = (const float*)d_in[10];
  const float* bn2_g = (const float*)d_in[11];
  const float* bn2_b = (const float*)d_in[12];
  const float* bn2_m = (const float*)d_in[13];
  const float* bn2_v = (const float*)d_in[14];
  const float* proj_w = (const float*)d_in[15];
  const float* bnp_g = (const float*)d_in[16];
  const float* bnp_b = (const float*)d_in[17];
  const float* bnp_m = (const float*)d_in[18];
  const float* bnp_v = (const float*)d_in[19];
  const float* kv_w = (const float*)d_in[20];
  const float* kvdw_w = (const float*)d_in[21];
  const float* out_w = (const float*)d_in[22];
  const float* temperature = (const float*)d_in[23];
  const float* a1 = (const float*)d_in[24];
  const float* a2 = (const float*)d_in[25];
  const float* a3 = (const float*)d_in[26];
  const float* a4 = (const float*)d_in[27];

  float* ws = (float*)d_ws;
  float* xrt = ws;
  float* qraw = ws + 204800;
  float* kv1t = ws + 409600;
  float* kinv = ws + 819200;
  float* vt = ws + 1024000;
  float* pewt = ws + 1228800;
  float* kvt = ws + 1245184;
  float* projt = ws + 1277952;
  float* qt = ws + 1228800;
  float* kt = ws + 1433600;
  float* xt = ws + 1638400;
  float* outA = ws + 1638400;
  float* w1t = ws + 1843200;
  float* w2t = ws + 1990656;
  float* outwt = ws + 2138112;

  k_prep<<<676, 256, 0, stream>>>(aspp_w1, aspp_w2, proj_w, kv_w, out_w, pe_w, x,
                                  w1t, w2t, projt, kvt, outwt, pewt, xt);
  k_pe_ln<<<400, 256, 0, stream>>>(xt, pewt, pe_b, ln_g, ln_b, xrt);
  k_aspp_kv1<<<1200, 256, 0, stream>>>(xrt, w1t, w2t, bn1_g, bn1_b, bn1_m, bn1_v,
                                       bn2_g, bn2_b, bn2_m, bn2_v, projt,
                                       bnp_g, bnp_b, bnp_m, bnp_v, qraw,
                                       kvt, kv1t);
  k_dw<<<928, 256, 0, stream>>>(kv1t, kvdw_w, kt, vt, qraw, qt);
  k_kinv<<<8, 256, 0, stream>>>(kt, kinv);
  k_attn<<<dim3(400, 8), 256, 0, stream>>>(qt, kt, vt, kinv, temperature,
                                           a1, a2, a3, a4, outA);
  k_fconv<<<400, 256, 0, stream>>>(outA, outwt, (float*)d_out);
}

// Round 16
// 202.227 us; speedup vs baseline: 1.0853x; 1.0853x over previous
//
#include <hip/hip_runtime.h>

#define NPOS 1600
#define DIMC 128
#define NHEADS 8
#define CHD 16

// ---------------- workspace layout (floats) ----------------
// 0        xrt     204800   (x + LN(pe(x)), position-major [1600][128])
// 204800   qraw    204800   (channel-major, pre-norm q)
// 409600   kv1t    409600   (1600 x 256, position-major)
// 819200   kbuf    204800   (channel-major, pre-norm k)
// 1024000  vt      204800   (position-major [h][m][16])
// 1228800  pewt    16384    \
// 1245184  kvt     32768     } transient (qt region)
// 1277952  projt   32768    /
// 1228800  qt      204800
// 1433600  kt      204800
// 1638400  xt/outA 204800
// 1843200  w1t     147456
// 1990656  w2t     147456
// 2138112  outwt   16384

__device__ __forceinline__ float wsum(float v) {
#pragma unroll
  for (int off = 1; off < 64; off <<= 1) v += __shfl_xor(v, off);
  return v;
}
// packed fp32 (2x rate)
__device__ __forceinline__ void pk_fma(float2& d, float2 a, float2 b) {
  asm("v_pk_fma_f32 %0, %1, %2, %0" : "+v"(d) : "v"(a), "v"(b));
}
__device__ __forceinline__ float2 pk_mul(float2 a, float2 b) {
  float2 d;
  asm("v_pk_mul_f32 %0, %1, %2" : "=v"(d) : "v"(a), "v"(b));
  return d;
}

// -------- one-time weight transposes + x transpose --------
__global__ __launch_bounds__(256) void k_prep(
    const float* __restrict__ w1, const float* __restrict__ w2,
    const float* __restrict__ proj, const float* __restrict__ kvw,
    const float* __restrict__ outw, const float* __restrict__ pew,
    const float* __restrict__ x,
    float* __restrict__ w1t, float* __restrict__ w2t,
    float* __restrict__ projt, float* __restrict__ kvt,
    float* __restrict__ outwt, float* __restrict__ pewt,
    float* __restrict__ xt) {
  int bid = blockIdx.x;
  int t = threadIdx.x;
  __shared__ float tile[DIMC][17];
  if (bid < 576) {
    int idx = bid * 256 + t;
    if (idx < 9 * DIMC * DIMC) {
      int k = idx / (DIMC * DIMC);
      int rem = idx % (DIMC * DIMC);
      int i = rem >> 7, o = rem & 127;
      w1t[idx] = w1[(o * DIMC + i) * 9 + k];
      w2t[idx] = w2[(o * DIMC + i) * 9 + k];
    }
    if (idx < 256 * DIMC) {
      int ic = idx >> 7, o = idx & 127;
      projt[idx] = proj[o * 256 + ic];
    }
    if (idx < DIMC * 256) {
      int i = idx >> 8, oc = idx & 255;
      kvt[idx] = kvw[oc * DIMC + i];
    }
    if (idx < DIMC * DIMC) {
      int i = idx >> 7, o = idx & 127;
      outwt[idx] = outw[o * DIMC + i];
      pewt[idx] = pew[o * DIMC + i];
    }
  } else {
    int n0 = (bid - 576) * 16;
#pragma unroll
    for (int pass = 0; pass < 2; pass++) {
      int ch = (t >> 2) + pass * 64, q = t & 3;
      float4 v = *(const float4*)(x + (size_t)ch * NPOS + n0 + q * 4);
      tile[ch][q * 4 + 0] = v.x; tile[ch][q * 4 + 1] = v.y;
      tile[ch][q * 4 + 2] = v.z; tile[ch][q * 4 + 3] = v.w;
    }
    __syncthreads();
    int pos = t >> 4, c8 = (t & 15) * 8;
#pragma unroll
    for (int k = 0; k < 8; k++)
      xt[(size_t)(n0 + pos) * DIMC + c8 + k] = tile[c8 + k][pos];
  }
}

// -------- pe (1x1 conv) + LayerNorm(ch) + residual; 256 threads, split-K --------
__global__ __launch_bounds__(256) void k_pe_ln(
    const float* __restrict__ xt, const float* __restrict__ pewt,
    const float* __restrict__ pb, const float* __restrict__ lg,
    const float* __restrict__ lb, float* __restrict__ xrt) {
  int n0 = blockIdx.x * 4;
  int t = threadIdx.x;
  int ch = t & 127, half = t >> 7;
  __shared__ __align__(16) float xc[4][DIMC];
  __shared__ float pacc[2][4][DIMC];
  __shared__ float red[2][2][4];
  if (t < 128) {
    int pos = t >> 5, c4 = t & 31;
    *(float4*)&xc[pos][c4 * 4] =
        *(const float4*)(xt + (size_t)(n0 + pos) * DIMC + c4 * 4);
  }
  __syncthreads();
  {
    float a[4] = {0.f, 0.f, 0.f, 0.f};
    int i0 = half * 64;
    for (int i = i0; i < i0 + 64; i++) {
      float wv = pewt[i * DIMC + ch];
#pragma unroll
      for (int p = 0; p < 4; p++) a[p] += wv * xc[p][i];
    }
#pragma unroll
    for (int p = 0; p < 4; p++) pacc[half][p][ch] = a[p];
  }
  __syncthreads();
  if (t < 128) {
    float pbv = pb[t];
    float acc[4];
#pragma unroll
    for (int p = 0; p < 4; p++) acc[p] = pacc[0][p][t] + pacc[1][p][t] + pbv;
    int w = t >> 6, lane = t & 63;
    {
      float s0 = wsum(acc[0]), s1 = wsum(acc[1]), s2 = wsum(acc[2]), s3 = wsum(acc[3]);
      if (lane == 0) { red[0][w][0] = s0; red[0][w][1] = s1; red[0][w][2] = s2; red[0][w][3] = s3; }
    }
    __builtin_amdgcn_wave_barrier();
    asm volatile("s_waitcnt lgkmcnt(0)" ::: "memory");
    __builtin_amdgcn_s_barrier();
    float mu[4];
#pragma unroll
    for (int p = 0; p < 4; p++) mu[p] = (red[0][0][p] + red[0][1][p]) * (1.f / 128.f);
    {
      float d0 = acc[0] - mu[0], d1 = acc[1] - mu[1], d2 = acc[2] - mu[2], d3 = acc[3] - mu[3];
      float q0 = wsum(d0 * d0), q1 = wsum(d1 * d1), q2 = wsum(d2 * d2), q3 = wsum(d3 * d3);
      if (lane == 0) { red[1][w][0] = q0; red[1][w][1] = q1; red[1][w][2] = q2; red[1][w][3] = q3; }
    }
    __builtin_amdgcn_wave_barrier();
    asm volatile("s_waitcnt lgkmcnt(0)" ::: "memory");
    __builtin_amdgcn_s_barrier();
    float lgv = lg[t], lbv = lb[t];
#pragma unroll
    for (int p = 0; p < 4; p++) {
      float var = (red[1][0][p] + red[1][1][p]) * (1.f / 128.f);
      float tv = (acc[p] - mu[p]) * rsqrtf(var + 1e-5f) * lgv + lbv;
      xrt[(size_t)(n0 + p) * DIMC + t] = xc[p][t] + tv;
    }
  } else {
    __builtin_amdgcn_s_barrier();
    __builtin_amdgcn_s_barrier();
  }
}

// -------- merged: ASPP+proj (0..799, 2-col strips) | kv 1x1 (800..1199) --------
__global__ __launch_bounds__(256) void k_aspp_kv1(
    const float* __restrict__ xrt, const float* __restrict__ w1t,
    const float* __restrict__ w2t, const float* __restrict__ bg1,
    const float* __restrict__ bb1, const float* __restrict__ bm1,
    const float* __restrict__ bv1, const float* __restrict__ bg2,
    const float* __restrict__ bb2, const float* __restrict__ bm2,
    const float* __restrict__ bv2, const float* __restrict__ projt,
    const float* __restrict__ bgp, const float* __restrict__ bbp,
    const float* __restrict__ bmp, const float* __restrict__ bvp,
    float* __restrict__ q,
    const float* __restrict__ kvt, float* __restrict__ kv1t) {
  int t = threadIdx.x;
  if (blockIdx.x < 800) {
    int strip = blockIdx.x;
    int r = strip / 20, c0 = (strip % 20) * 2;
    int ch = t & 127, br = t >> 7;
    __shared__ __align__(16) float xs[2][DIMC][2];
    __shared__ __align__(16) float cat[2 * DIMC][2];
    float aa[2] = {0.f, 0.f};
    int dil = br ? 5 : 3;
    const float* wt = br ? w2t : w1t;
    for (int k = 0; k < 9; k++) {
      int dr = k / 3 - 1, dc = k % 3 - 1;
      int rr = r + dil * dr;
#pragma unroll
      for (int p = 0; p < 2; p++) {
        int cc = c0 + p + dil * dc;
        xs[br][ch][p] = (rr >= 0 && rr < 40 && cc >= 0 && cc < 40)
                            ? xrt[(size_t)(rr * 40 + cc) * DIMC + ch] : 0.f;
      }
      __syncthreads();
      const float* wrow = wt + (size_t)k * DIMC * DIMC + ch;
      for (int i = 0; i < DIMC; i++) {
        float wv = wrow[i * DIMC];
        aa[0] += wv * xs[br][i][0];
        aa[1] += wv * xs[br][i][1];
      }
      __syncthreads();
    }
    float sc = br ? bg2[ch] * rsqrtf(bv2[ch] + 1e-5f) : bg1[ch] * rsqrtf(bv1[ch] + 1e-5f);
    float bm = br ? bm2[ch] : bm1[ch];
    float bb = br ? bb2[ch] : bb1[ch];
#pragma unroll
    for (int p = 0; p < 2; p++) cat[br * DIMC + ch][p] = fmaxf((aa[p] - bm) * sc + bb, 0.f);
    __syncthreads();
    float qa = 0.f;
    for (int j = 0; j < 256; j++) {
      float wv = projt[j * DIMC + ch];
      qa += wv * cat[j][br];
    }
    float scp = bgp[ch] * rsqrtf(bvp[ch] + 1e-5f);
    q[ch * NPOS + r * 40 + c0 + br] = fmaxf((qa - bmp[ch]) * scp + bbp[ch], 0.f);
  } else {
    int n0 = (blockIdx.x - 800) * 4;
    __shared__ __align__(16) float xc[4][DIMC];
    if (t < 128) {
      int pos = t >> 5, c4 = t & 31;
      *(float4*)&xc[pos][c4 * 4] =
          *(const float4*)(xrt + (size_t)(n0 + pos) * DIMC + c4 * 4);
    }
    __syncthreads();
    float acc[4] = {0.f, 0.f, 0.f, 0.f};
    for (int i = 0; i < DIMC; i++) {
      float w = kvt[i * 256 + t];
#pragma unroll
      for (int p = 0; p < 4; p++) acc[p] += w * xc[p][i];
    }
#pragma unroll
    for (int p = 0; p < 4; p++) kv1t[(n0 + p) * 256 + t] = acc[p];
  }
}

// -------- depthwise 3x3 (0..799, 2-col strips) | q L2-norm (800..927) --------
__global__ __launch_bounds__(256) void k_dw(const float* __restrict__ kv1t,
                                            const float* __restrict__ dww,
                                            float* __restrict__ kbuf,
                                            float* __restrict__ vt,
                                            const float* __restrict__ qraw,
                                            float* __restrict__ qt) {
  int t = threadIdx.x;
  if (blockIdx.x < 800) {
    int strip = blockIdx.x;
    int r = strip / 20, c0 = (strip % 20) * 2;
    float wl[9];
#pragma unroll
    for (int k = 0; k < 9; k++) wl[k] = dww[t * 9 + k];
    __builtin_amdgcn_s_setprio(1);
    for (int p = 0; p < 2; p++) {
      int c = c0 + p;
      float acc = 0.f;
#pragma unroll
      for (int kh = 0; kh < 3; kh++) {
        int rr = r + kh - 1;
        if (rr < 0 || rr >= 40) continue;
#pragma unroll
        for (int kw_ = 0; kw_ < 3; kw_++) {
          int cc = c + kw_ - 1;
          if (cc < 0 || cc >= 40) continue;
          acc += wl[kh * 3 + kw_] * kv1t[(rr * 40 + cc) * 256 + t];
        }
      }
      int pos = r * 40 + c;
      if (t < DIMC) {
        kbuf[t * NPOS + pos] = acc;
      } else {
        int cv = t - DIMC;
        vt[((size_t)(cv >> 4) * NPOS + pos) * CHD + (cv & 15)] = acc;
      }
    }
    __builtin_amdgcn_s_setprio(0);
  } else {
    // q-channel L2 norm (depends only on qraw, concurrent with dw work)
    int ch = blockIdx.x - 800;
    __shared__ float wred[4];
    float ss = 0.f;
    for (int m = t; m < NPOS; m += 256) {
      float v = qraw[ch * NPOS + m];
      ss += v * v;
    }
    ss = wsum(ss);
    if ((t & 63) == 0) wred[t >> 6] = ss;
    __syncthreads();
    float tot = wred[0] + wred[1] + wred[2] + wred[3];
    float inv = 1.0f / fmaxf(sqrtf(tot), 1e-12f);
    int h = ch >> 4, c = ch & 15;
    for (int m = t; m < NPOS; m += 256)
      qt[((size_t)(h * NPOS) + m) * CHD + c] = qraw[ch * NPOS + m] * inv;
  }
}

// -------- per-channel L2 norm for k only --------
__global__ __launch_bounds__(256) void k_norm(const float* __restrict__ kbuf,
                                              float* __restrict__ kt) {
  int ch = blockIdx.x, t = threadIdx.x;
  __shared__ float wred[4];
  float ss = 0.f;
  for (int m = t; m < NPOS; m += 256) {
    float v = kbuf[ch * NPOS + m];
    ss += v * v;
  }
  ss = wsum(ss);
  if ((t & 63) == 0) wred[t >> 6] = ss;
  __syncthreads();
  float tot = wred[0] + wred[1] + wred[2] + wred[3];
  float inv = 1.0f / fmaxf(sqrtf(tot), 1e-12f);
  int h = ch >> 4, c = ch & 15;
  for (int m = t; m < NPOS; m += 256)
    kt[((size_t)(h * NPOS) + m) * CHD + c] = kbuf[ch * NPOS + m] * inv;
}

// -------- fused attention: 4 rows/block, wave-per-row select --------
#define RANK_STEP(INCL, S0, S1, S2, S3, REM, TT)                         \
  {                                                                      \
    int abv = (INCL) - (S0);                                             \
    int ge1 = abv + (S1), ge2 = abv + (S2), ge3 = abv + (S3);            \
    bool hit = ((INCL) >= (REM)) && (abv < (REM));                       \
    bool c0_ = hit && (ge1 < (REM));                                     \
    bool c1_ = hit && (ge1 >= (REM)) && (ge2 < (REM));                   \
    bool c2_ = hit && (ge2 >= (REM)) && (ge3 < (REM));                   \
    int bl = c0_ ? 4 * lane : c1_ ? 4 * lane + 1                         \
           : c2_ ? 4 * lane + 2 : 4 * lane + 3;                          \
    int gl = c0_ ? ge1 : c1_ ? ge2 : c2_ ? ge3 : abv;                    \
    unsigned long long bal = __ballot(hit);                              \
    int wl = (int)__ffsll(bal) - 1;                                      \
    TT |= ((unsigned)__shfl(bl, wl)) << ls;                              \
    REM -= __shfl(gl, wl);                                               \
  }

__device__ __forceinline__ float dec_u(unsigned uu) {
  int bits = (uu & 0x80000000u) ? (int)(uu ^ 0x80000000u) : (int)(~uu);
  return __int_as_float(bits);
}

__global__ __launch_bounds__(256) void k_attn(
    const float* __restrict__ qt, const float* __restrict__ kt,
    const float* __restrict__ vt, const float* __restrict__ temp,
    const float* __restrict__ a1p, const float* __restrict__ a2p,
    const float* __restrict__ a3p, const float* __restrict__ a4p,
    float* __restrict__ outA) {
  __shared__ unsigned hist[2][4][4][256];  // [buf][row][group|copy][bin], 32 KB
  __shared__ unsigned s_thr[4][4];
  __shared__ float s_z[4][16];
  __shared__ float s_wr[4][64];

  int tid = threadIdx.x;
  int lane = tid & 63, w = tid >> 6;
  int n0 = blockIdx.x * 4;
  int h = blockIdx.y;

  float tmpr = temp[h];
  const float* kbase = kt + (size_t)h * NPOS * CHD;
  const float* vbase = vt + (size_t)h * NPOS * CHD;

  float2 qreg[4][8];
  {
    const float4* q4 = (const float4*)(qt + ((size_t)h * NPOS + n0) * CHD);
#pragma unroll
    for (int r = 0; r < 4; r++)
#pragma unroll
      for (int j = 0; j < 4; j++) {
        float4 a = q4[r * 4 + j];
        qreg[r][2 * j] = make_float2(a.x, a.y);
        qreg[r][2 * j + 1] = make_float2(a.z, a.w);
      }
  }

#pragma unroll
  for (int k = 0; k < 4; k++) ((uint4*)hist)[tid + k * 256] = make_uint4(0u, 0u, 0u, 0u);

  unsigned u[4][7];
  __builtin_amdgcn_s_setprio(1);
#pragma unroll
  for (int i = 0; i < 7; i++) {
    int m = tid + (i << 8);
    const float4* k4 = (const float4*)(kbase + (size_t)m * CHD);
    float4 ka = k4[0], kb = k4[1], kc = k4[2], kd = k4[3];
    bool valid = (m < NPOS);
#pragma unroll
    for (int r = 0; r < 4; r++) {
      float2 e = pk_mul(make_float2(ka.x, ka.y), qreg[r][0]);
      pk_fma(e, make_float2(ka.z, ka.w), qreg[r][1]);
      pk_fma(e, make_float2(kb.x, kb.y), qreg[r][2]);
      pk_fma(e, make_float2(kb.z, kb.w), qreg[r][3]);
      pk_fma(e, make_float2(kc.x, kc.y), qreg[r][4]);
      pk_fma(e, make_float2(kc.z, kc.w), qreg[r][5]);
      pk_fma(e, make_float2(kd.x, kd.y), qreg[r][6]);
      pk_fma(e, make_float2(kd.z, kd.w), qreg[r][7]);
      float s = (e.x + e.y) * tmpr;
      int bi = __float_as_int(s);
      unsigned uu = ((unsigned)bi) ^ ((bi < 0) ? 0xFFFFFFFFu : 0x80000000u);
      u[r][i] = valid ? uu : 0x00800000u;
    }
  }
  __builtin_amdgcn_s_setprio(0);
  __syncthreads();

  unsigned tw0 = 0, tw1 = 0, tw2 = 0, tw3 = 0;
  int rw0 = 800, rw1 = 1066, rw2 = 1200, rw3 = 1280;

#pragma unroll
  for (int level = 3; level >= 1; level--) {
    const int ls = level * 8;
    const unsigned pm = (level == 3) ? 0u : (0xFFFFFFFFu << (ls + 8));
    const int p = (3 - level) & 1;

    if (level == 3) {
      int cpy = ((w & 1) << 1) | (lane & 1);
#pragma unroll
      for (int i = 0; i < 7; i++)
#pragma unroll
        for (int r = 0; r < 4; r++)
          atomicAdd(&hist[p][r][cpy][u[r][i] >> 24], 1u);
    } else {
      unsigned P[4][4];
#pragma unroll
      for (int r = 0; r < 4; r++)
#pragma unroll
        for (int g = 0; g < 4; g++) P[r][g] = s_thr[r][g] & pm;
#pragma unroll
      for (int i = 0; i < 7; i++)
#pragma unroll
        for (int r = 0; r < 4; r++) {
          unsigned uu = u[r][i], pf = uu & pm;
          int g = (pf == P[r][0]) ? 0 : (pf == P[r][1]) ? 1 : (pf == P[r][2]) ? 2
                : (pf == P[r][3]) ? 3 : -1;
          if (g >= 0) atomicAdd(&hist[p][r][g][(uu >> ls) & 255], 1u);
        }
    }
    __syncthreads();

    if (level != 1) {
#pragma unroll
      for (int k = 0; k < 4; k++)
        ((uint4*)(&hist[p ^ 1][0][0][0]))[tid + k * 256] = make_uint4(0u, 0u, 0u, 0u);
    }

    uint4 c0 = *(const uint4*)&hist[p][w][0][lane * 4];
    uint4 c1 = *(const uint4*)&hist[p][w][1][lane * 4];
    uint4 c2 = *(const uint4*)&hist[p][w][2][lane * 4];
    uint4 c3 = *(const uint4*)&hist[p][w][3][lane * 4];
    bool L1, L2, L3;
    if (level == 3) {
      c0.x += c1.x + c2.x + c3.x;
      c0.y += c1.y + c2.y + c3.y;
      c0.z += c1.z + c2.z + c3.z;
      c0.w += c1.w + c2.w + c3.w;
      c1 = make_uint4(0u, 0u, 0u, 0u); c2 = c1; c3 = c1;
      L1 = false; L2 = false; L3 = false;
    } else {
      L1 = ((tw1 & pm) != (tw0 & pm));
      L2 = ((tw2 & pm) != (tw1 & pm));
      L3 = ((tw3 & pm) != (tw2 & pm));
    }

    int s3_0 = c0.w, s2_0 = s3_0 + c0.z, s1_0 = s2_0 + c0.y, s0_0 = s1_0 + c0.x;
    int s3_1 = c1.w, s2_1 = s3_1 + c1.z, s1_1 = s2_1 + c1.y, s0_1 = s1_1 + c1.x;
    int s3_2 = c2.w, s2_2 = s3_2 + c2.z, s1_2 = s2_2 + c2.y, s0_2 = s1_2 + c2.x;
    int s3_3 = c3.w, s2_3 = s3_3 + c3.z, s1_3 = s2_3 + c3.y, s0_3 = s1_3 + c3.x;

    unsigned vA = (unsigned)s0_0 | ((unsigned)s0_1 << 16);
    unsigned vB = (unsigned)s0_2 | ((unsigned)s0_3 << 16);
#pragma unroll
    for (int off = 1; off < 64; off <<= 1) {
      unsigned xA = __shfl_down(vA, off), xB = __shfl_down(vB, off);
      if (lane + off < 64) { vA += xA; vB += xB; }
    }
    int i0 = (int)(vA & 0xFFFFu), i1 = (int)(vA >> 16);
    int i2 = (int)(vB & 0xFFFFu), i3 = (int)(vB >> 16);

    RANK_STEP(i0, s0_0, s1_0, s2_0, s3_0, rw0, tw0);
    int I1 = L1 ? i1 : i0;
    int S0a = L1 ? s0_1 : s0_0, S1a = L1 ? s1_1 : s1_0;
    int S2a = L1 ? s2_1 : s2_0, S3a = L1 ? s3_1 : s3_0;
    RANK_STEP(I1, S0a, S1a, S2a, S3a, rw1, tw1);
    int I2 = L2 ? i2 : I1;
    int S0b = L2 ? s0_2 : S0a, S1b = L2 ? s1_2 : S1a;
    int S2b = L2 ? s2_2 : S2a, S3b = L2 ? s3_2 : S3a;
    RANK_STEP(I2, S0b, S1b, S2b, S3b, rw2, tw2);
    int I3 = L3 ? i3 : I2;
    int S0c = L3 ? s0_3 : S0b, S1c = L3 ? s1_3 : S1b;
    int S2c = L3 ? s2_3 : S2b, S3c = L3 ? s3_3 : S3b;
    RANK_STEP(I3, S0c, S1c, S2c, S3c, rw3, tw3);

    if (lane == 0) {
      s_thr[w][0] = tw0; s_thr[w][1] = tw1;
      s_thr[w][2] = tw2; s_thr[w][3] = tw3;
    }
    __syncthreads();
  }

  unsigned tr[4][4];
#pragma unroll
  for (int r = 0; r < 4; r++)
#pragma unroll
    for (int j = 0; j < 4; j++) tr[r][j] = s_thr[r][j];
  float C[4];
#pragma unroll
  for (int r = 0; r < 4; r++) C[r] = dec_u(tr[r][0]);

  float zacc[4][4];
#pragma unroll
  for (int r = 0; r < 4; r++)
#pragma unroll
    for (int j = 0; j < 4; j++) zacc[r][j] = 0.f;
#pragma unroll
  for (int i = 0; i < 7; i++) {
#pragma unroll
    for (int r = 0; r < 4; r++) {
      unsigned uu = u[r][i];
      float e = __expf(dec_u(uu) - C[r]);
      int b; float ee;
      if (uu >= tr[r][1]) { b = (uu >= tr[r][0]) ? 0 : 1; ee = e; }
      else if (uu >= tr[r][3]) { b = (uu >= tr[r][2]) ? 2 : 3; ee = e; }
      else { b = 3; ee = 0.f; }
      zacc[r][0] += (b == 0) ? ee : 0.f;
      zacc[r][1] += (b <= 1) ? ee : 0.f;
      zacc[r][2] += (b <= 2) ? ee : 0.f;
      zacc[r][3] += ee;
      u[r][i] = (__float_as_uint(ee) & ~3u) | (unsigned)b;
    }
  }
  {
    float zv[16];
#pragma unroll
    for (int r = 0; r < 4; r++)
#pragma unroll
      for (int j = 0; j < 4; j++) zv[r * 4 + j] = zacc[r][j];
#pragma unroll
    for (int k = 0; k < 8; k++) {
      float s = (lane & 1) ? zv[k] : zv[k + 8];
      float x = __shfl_xor(s, 1);
      zv[k] = ((lane & 1) ? zv[k + 8] : zv[k]) + x;
    }
#pragma unroll
    for (int k = 0; k < 4; k++) {
      float s = (lane & 2) ? zv[k] : zv[k + 4];
      float x = __shfl_xor(s, 2);
      zv[k] = ((lane & 2) ? zv[k + 4] : zv[k]) + x;
    }
#pragma unroll
    for (int k = 0; k < 2; k++) {
      float s = (lane & 4) ? zv[k] : zv[k + 2];
      float x = __shfl_xor(s, 4);
      zv[k] = ((lane & 4) ? zv[k + 2] : zv[k]) + x;
    }
    {
      float s = (lane & 8) ? zv[0] : zv[1];
      float x = __shfl_xor(s, 8);
      zv[0] = ((lane & 8) ? zv[1] : zv[0]) + x;
    }
    zv[0] += __shfl_xor(zv[0], 16);
    zv[0] += __shfl_xor(zv[0], 32);
    int zidx = ((lane & 1) << 3) | ((lane & 2) << 1) | ((lane & 4) >> 1) | ((lane & 8) >> 3);
    if (lane < 16) s_z[w][zidx] = zv[0];
  }
  __syncthreads();
  float coef[4][4];
  {
    float A1 = a1p[0], A2 = a2p[0], A3 = a3p[0], A4 = a4p[0];
#pragma unroll
    for (int r = 0; r < 4; r++) {
      float Z0 = s_z[0][r * 4 + 0] + s_z[1][r * 4 + 0] + s_z[2][r * 4 + 0] + s_z[3][r * 4 + 0];
      float Z1 = s_z[0][r * 4 + 1] + s_z[1][r * 4 + 1] + s_z[2][r * 4 + 1] + s_z[3][r * 4 + 1];
      float Z2 = s_z[0][r * 4 + 2] + s_z[1][r * 4 + 2] + s_z[2][r * 4 + 2] + s_z[3][r * 4 + 2];
      float Z3 = s_z[0][r * 4 + 3] + s_z[1][r * 4 + 3] + s_z[2][r * 4 + 3] + s_z[3][r * 4 + 3];
      float c3 = A4 / Z3;
      float c2 = c3 + A3 / Z2;
      float c1 = c2 + A2 / Z1;
      float c0 = c1 + A1 / Z0;
      coef[r][0] = c0; coef[r][1] = c1; coef[r][2] = c2; coef[r][3] = c3;
    }
  }

  float2 o[4][8];
#pragma unroll
  for (int r = 0; r < 4; r++)
#pragma unroll
    for (int j = 0; j < 8; j++) o[r][j] = make_float2(0.f, 0.f);
  __builtin_amdgcn_s_setprio(1);
#pragma unroll
  for (int i = 0; i < 7; i++) {
    int m = tid + (i << 8);
    const float4* v4 = (const float4*)(vbase + (size_t)m * CHD);
    float4 va = v4[0], vb = v4[1], vc = v4[2], vd = v4[3];
#pragma unroll
    for (int r = 0; r < 4; r++) {
      unsigned pe = u[r][i];
      int b = pe & 3;
      float wg = __uint_as_float(pe & ~3u)
               * ((b == 0) ? coef[r][0] : (b == 1) ? coef[r][1] : (b == 2) ? coef[r][2] : coef[r][3]);
      float2 w2 = make_float2(wg, wg);
      pk_fma(o[r][0], make_float2(va.x, va.y), w2);
      pk_fma(o[r][1], make_float2(va.z, va.w), w2);
      pk_fma(o[r][2], make_float2(vb.x, vb.y), w2);
      pk_fma(o[r][3], make_float2(vb.z, vb.w), w2);
      pk_fma(o[r][4], make_float2(vc.x, vc.y), w2);
      pk_fma(o[r][5], make_float2(vc.z, vc.w), w2);
      pk_fma(o[r][6], make_float2(vd.x, vd.y), w2);
      pk_fma(o[r][7], make_float2(vd.z, vd.w), w2);
    }
  }
  __builtin_amdgcn_s_setprio(0);
  {
    float rr[64];
#pragma unroll
    for (int r = 0; r < 4; r++)
#pragma unroll
      for (int j = 0; j < 8; j++) {
        rr[r * 16 + 2 * j] = o[r][j].x;
        rr[r * 16 + 2 * j + 1] = o[r][j].y;
      }
#pragma unroll
    for (int k = 0; k < 32; k++) {
      float s = (lane & 1) ? rr[k] : rr[k + 32];
      float x = __shfl_xor(s, 1);
      rr[k] = ((lane & 1) ? rr[k + 32] : rr[k]) + x;
    }
#pragma unroll
    for (int k = 0; k < 16; k++) {
      float s = (lane & 2) ? rr[k] : rr[k + 16];
      float x = __shfl_xor(s, 2);
      rr[k] = ((lane & 2) ? rr[k + 16] : rr[k]) + x;
    }
#pragma unroll
    for (int k = 0; k < 8; k++) {
      float s = (lane & 4) ? rr[k] : rr[k + 8];
      float x = __shfl_xor(s, 4);
      rr[k] = ((lane & 4) ? rr[k + 8] : rr[k]) + x;
    }
#pragma unroll
    for (int k = 0; k < 4; k++) {
      float s = (lane & 8) ? rr[k] : rr[k + 4];
      float x = __shfl_xor(s, 8);
      rr[k] = ((lane & 8) ? rr[k + 4] : rr[k]) + x;
    }
#pragma unroll
    for (int k = 0; k < 2; k++) {
      float s = (lane & 16) ? rr[k] : rr[k + 2];
      float x = __shfl_xor(s, 16);
      rr[k] = ((lane & 16) ? rr[k + 2] : rr[k]) + x;
    }
    {
      float s = (lane & 32) ? rr[0] : rr[1];
      float x = __shfl_xor(s, 32);
      rr[0] = ((lane & 32) ? rr[1] : rr[0]) + x;
    }
    int idx = ((lane & 1) << 5) | ((lane & 2) << 3) | ((lane & 4) << 1)
            | ((lane & 8) >> 1) | ((lane & 16) >> 3) | ((lane & 32) >> 5);
    s_wr[w][idx] = rr[0];
  }
  __syncthreads();
  if (tid < 64) {
    float v = s_wr[0][tid] + s_wr[1][tid] + s_wr[2][tid] + s_wr[3][tid];
    outA[((size_t)h * NPOS + n0) * CHD + tid] = v;
  }
}

// -------- final 1x1 conv; 256 threads, split-K --------
__global__ __launch_bounds__(256) void k_fconv(const float* __restrict__ outA,
                                               const float* __restrict__ outwt,
                                               float* __restrict__ y) {
  int n0 = blockIdx.x * 4;
  int t = threadIdx.x;
  int ch = t & 127, half = t >> 7;
  __shared__ __align__(16) float oc[4][DIMC];
  __shared__ float pacc[2][4][DIMC];
  if (t < 128) {
    int pos = t >> 5, ch4 = t & 31;
    int head = ch4 >> 2, qq = ch4 & 3;
    float4 v = *(const float4*)(outA + ((size_t)(head * NPOS) + n0 + pos) * CHD + qq * 4);
    *(float4*)&oc[pos][ch4 * 4] = v;
  }
  __syncthreads();
  {
    float a[4] = {0.f, 0.f, 0.f, 0.f};
    int i0 = half * 64;
    for (int i = i0; i < i0 + 64; i++) {
      float wv = outwt[i * DIMC + ch];
#pragma unroll
      for (int p = 0; p < 4; p++) a[p] += wv * oc[p][i];
    }
#pragma unroll
    for (int p = 0; p < 4; p++) pacc[half][p][ch] = a[p];
  }
  __syncthreads();
  if (t < 128) {
#pragma unroll
    for (int p = 0; p < 4; p++)
      y[t * NPOS + n0 + p] = pacc[0][p][t] + pacc[1][p][t];
  }
}

extern "C" void kernel_launch(void* const* d_in, const int* in_sizes, int n_in,
                              void* d_out, int out_size, void* d_ws, size_t ws_size,
                              hipStream_t stream) {
  const float* x = (const float*)d_in[0];
  const float* pe_w = (const float*)d_in[1];
  const float* pe_b = (const float*)d_in[2];
  const float* ln_g = (const float*)d_in[3];
  const float* ln_b = (const float*)d_in[4];
  const float* aspp_w1 = (const float*)d_in[5];
  const float* bn1_g = (const float*)d_in[6];
  const float* bn1_b = (const float*)d_in[7];
  const float* bn1_m = (const float*)d_in[8];
  const float* bn1_v = (const float*)d_in[9];
  const float* aspp_w2 = (const float*)d_in[10];
  const float* bn2_g = (const float*)d_in[11];
  const float* bn2_b = (const float*)d_in[12];
  const float* bn2_m = (const float*)d_in[13];
  const float* bn2_v = (const float*)d_in[14];
  const float* proj_w = (const float*)d_in[15];
  const float* bnp_g = (const float*)d_in[16];
  const float* bnp_b = (const float*)d_in[17];
  const float* bnp_m = (const float*)d_in[18];
  const float* bnp_v = (const float*)d_in[19];
  const float* kv_w = (const float*)d_in[20];
  const float* kvdw_w = (const float*)d_in[21];
  const float* out_w = (const float*)d_in[22];
  const float* temperature = (const float*)d_in[23];
  const float* a1 = (const float*)d_in[24];
  const float* a2 = (const float*)d_in[25];
  const float* a3 = (const float*)d_in[26];
  const float* a4 = (const float*)d_in[27];

  float* ws = (float*)d_ws;
  float* xrt = ws;
  float* qraw = ws + 204800;
  float* kv1t = ws + 409600;
  float* kbuf = ws + 819200;
  float* vt = ws + 1024000;
  float* pewt = ws + 1228800;
  float* kvt = ws + 1245184;
  float* projt = ws + 1277952;
  float* qt = ws + 1228800;
  float* kt = ws + 1433600;
  float* xt = ws + 1638400;
  float* outA = ws + 1638400;
  float* w1t = ws + 1843200;
  float* w2t = ws + 1990656;
  float* outwt = ws + 2138112;

  k_prep<<<676, 256, 0, stream>>>(aspp_w1, aspp_w2, proj_w, kv_w, out_w, pe_w, x,
                                  w1t, w2t, projt, kvt, outwt, pewt, xt);
  k_pe_ln<<<400, 256, 0, stream>>>(xt, pewt, pe_b, ln_g, ln_b, xrt);
  k_aspp_kv1<<<1200, 256, 0, stream>>>(xrt, w1t, w2t, bn1_g, bn1_b, bn1_m, bn1_v,
                                       bn2_g, bn2_b, bn2_m, bn2_v, projt,
                                       bnp_g, bnp_b, bnp_m, bnp_v, qraw,
                                       kvt, kv1t);
  k_dw<<<928, 256, 0, stream>>>(kv1t, kvdw_w, kbuf, vt, qraw, qt);
  k_norm<<<128, 256, 0, stream>>>(kbuf, kt);
  k_attn<<<dim3(400, 8), 256, 0, stream>>>(qt, kt, vt, temperature, a1, a2, a3, a4, outA);
  k_fconv<<<400, 256, 0, stream>>>(outA, outwt, (float*)d_out);
}